// Round 2
// baseline (2475.416 us; speedup 1.0000x reference)
//
#include <hip/hip_runtime.h>
#include <stdint.h>

#define SLEN    512
#define IDIM    256
#define HDIM    512
#define NROW    256          // 2 sequences x 128 batch rows
#define KP      776          // Ab LDS row stride in halfs (768 + 8)
#define NSTEP   512
#define NGRP    16           // batch groups (16 rows each)
#define GWG     16           // WGs (column groups) per batch group

typedef __attribute__((ext_vector_type(8))) _Float16 half8;
typedef __attribute__((ext_vector_type(4))) float   f32x4;

__device__ __forceinline__ float sigm(float x)   { return 1.0f / (1.0f + __expf(-x)); }
__device__ __forceinline__ float tanh_f(float x) { return 2.0f / (1.0f + __expf(-2.0f * x)) - 1.0f; }

__device__ __forceinline__ half8 cvt8(float4 a, float4 b) {
    half8 v;
    v[0] = (_Float16)a.x; v[1] = (_Float16)a.y; v[2] = (_Float16)a.z; v[3] = (_Float16)a.w;
    v[4] = (_Float16)b.x; v[5] = (_Float16)b.y; v[6] = (_Float16)b.z; v[7] = (_Float16)b.w;
    return v;
}

union hu { _Float16 h; unsigned short u; };

// Persistent LSTM, dual-group software pipeline.
// 128 WGs = 8 group-PAIRS x 16 column groups. Each WG runs two batch groups
// (A = 2p, B = 2p+1) in alternating half-steps: group A's LLC exchange latency
// hides under group B's compute and vice versa.
// Round-2 changes vs round 1:
//  - dual-group pipeline (the big one): flags are posted one full body before
//    they are needed -> pre-issued flag load makes detect ~0.
//  - h staging via global_load_lds (aux=17 = sc0|sc1): issued right after the
//    flag check, drained after the x-GEMM -> h-load latency hidden; removes
//    the scatter ds_writes (bank conflicts) and the VGPR round trip.
//  - deferred store drain: h stores issue at body end, vmcnt(0) at next body
//    top drains them, THEN posts the previous group's flag (still a full body
//    ahead of peer need).
//  - one barrier per body (the old A1 is subsumed by the other group's A2).
__global__ __launch_bounds__(256, 1)
void lstm_persistent(const float* __restrict__ x0, const float* __restrict__ x1,
                     const float* __restrict__ wih, const float* __restrict__ whh,
                     const float* __restrict__ bih, const float* __restrict__ bhh,
                     _Float16* __restrict__ hb, int* __restrict__ flg,
                     float* __restrict__ out) {
    __shared__ __align__(16) _Float16 Ab[2][16 * KP];

    const int tid  = threadIdx.x;
    const int lane = tid & 63;
    const int w    = tid >> 6;       // wave 0..3
    const int quad = lane >> 4;
    const int l16  = lane & 15;
    const int pair = blockIdx.x & 7;     // group pair (groups 2p, 2p+1)
    const int jcg  = blockIdx.x >> 3;    // column group (32 H-cols), 0..15

    // ---- W A-frags: global fp32 -> f16 regs/AGPRs, once (jcg-dependent only) ----
    const int q0  = l16 & 3, ccl = l16 >> 2;
    const int colb = jcg * 32 + w * 8 + ccl * 2;
    const int gc0 = q0 * HDIM + colb;
    const int gc1 = gc0 + 1;
    half8 wf0[24], wf1[24];
#pragma unroll
    for (int kk = 0; kk < 24; ++kk) {
        int k0 = kk * 32 + quad * 8;
        const float* sA = (k0 < IDIM) ? wih + (size_t)gc0 * IDIM + k0
                                      : whh + (size_t)gc0 * HDIM + (k0 - IDIM);
        const float* sB = (k0 < IDIM) ? wih + (size_t)gc1 * IDIM + k0
                                      : whh + (size_t)gc1 * HDIM + (k0 - IDIM);
        wf0[kk] = cvt8(*(const float4*)sA, *(const float4*)(sA + 4));
        wf1[kk] = cvt8(*(const float4*)sB, *(const float4*)(sB + 4));
    }

    float bias0[4], bias1[4];
#pragma unroll
    for (int q = 0; q < 4; ++q) {
        int g0 = q * HDIM + jcg * 32 + w * 8 + quad * 2;
        bias0[q] = bih[g0] + bhh[g0];
        bias1[q] = bih[g0 + 1] + bhh[g0 + 1];
    }

    const int r0  = tid >> 5;            // my x rows r0, r0+8
    const int o0  = (tid & 31) * 8;      // my x col chunk
    const int cc0 = jcg * 32 + w * 8 + quad * 2;   // my H-cols (cc0, cc0+1)

    const int igrps[2] = { pair * 2, pair * 2 + 1 };
    const float* xps[2];
    xps[0] = (igrps[0] < 8) ? x0 : x1;
    xps[1] = (igrps[1] < 8) ? x0 : x1;
    const int brows[2] = { (igrps[0] & 7) * 16, (igrps[1] & 7) * 16 };
    const int grows[2] = { igrps[0] * 16 + l16, igrps[1] * 16 + l16 };
    const int* fpolls[2] = { flg + igrps[0] * 64 + lane, flg + igrps[1] * 64 + lane };
    int* fmines[2] = { flg + igrps[0] * 64 + jcg * 4 + w,
                       flg + igrps[1] * 64 + jcg * 4 + w };

    float cr0[2] = {0.f, 0.f}, cr1[2] = {0.f, 0.f};
    int pf = 0;       // pre-issued flag value for the NEXT body
    int gaveup = 0;   // spin-timeout failsafe

    // ---- prologue: stage x(0) for both groups ----
#pragma unroll
    for (int s = 0; s < 2; ++s) {
        const float* xr0 = xps[s] + ((size_t)(brows[s] + r0) * SLEN + 0) * IDIM + o0;
        const float* xr1 = xr0 + (size_t)8 * SLEN * IDIM;
        float4 pa = *(const float4*)xr0, pb = *(const float4*)(xr0 + 4);
        float4 pc = *(const float4*)xr1, pd = *(const float4*)(xr1 + 4);
        *(half8*)&Ab[s][r0 * KP + o0]       = cvt8(pa, pb);
        *(half8*)&Ab[s][(r0 + 8) * KP + o0] = cvt8(pc, pd);
    }
    __syncthreads();

#pragma unroll 1
    for (int t = 0; t < NSTEP; ++t) {
#pragma unroll
        for (int s = 0; s < 2; ++s) {
            // ---- top: drain prev body's h stores (+pf); post prev group's flag ----
            if (!(t == 0 && s == 0)) {
                asm volatile("s_waitcnt vmcnt(0)" ::: "memory");
                __builtin_amdgcn_sched_barrier(0);
                if (lane == 0) {
                    int fv = s ? (t + 1) : t;    // value for the previous group
                    asm volatile("global_store_dword %0, %1, off sc0 sc1"
                                 :: "v"(fmines[1 - s]), "v"(fv) : "memory");
                }
            }
            // ---- my group's flag check (pre-loaded; poll fallback) ----
            if (t > 0 && !gaveup) {
                if (!__all(pf >= t)) {
                    int it = 0;
                    while (true) {
                        int f;
                        asm volatile("global_load_dword %0, %1, off sc0 sc1\n\t"
                                     "s_waitcnt vmcnt(0)"
                                     : "=v"(f) : "v"(fpolls[s]) : "memory");
                        if (__all(f >= t)) break;
                        __builtin_amdgcn_s_sleep(1);
                        if (++it > (1 << 20)) { gaveup = 1; break; }
                    }
                }
                __builtin_amdgcn_fence(__ATOMIC_ACQUIRE, "workgroup");
            }
            // ---- issue h_{t-1} staging: 4x global_load_lds (one full Ab row each) ----
            {
                const _Float16* hsrc = hb + (size_t)((t + 1) & 1) * (NROW * HDIM)
                                          + (size_t)(igrps[s] * 16) * HDIM;
#pragma unroll
                for (int p = 0; p < 4; ++p) {
                    const int r = p * 4 + w;
                    const _Float16* g = hsrc + (size_t)r * HDIM + lane * 8;
                    __builtin_amdgcn_global_load_lds(
                        (const __attribute__((address_space(1))) void*)g,
                        (__attribute__((address_space(3))) void*)&Ab[s][r * KP + IDIM],
                        16, 0, 17 /* sc0|sc1 */);
                }
            }
            // ---- x(t+1) prefetch issue (off-chain) ----
            float4 pa, pb, pc, pd;
            if (t < NSTEP - 1) {
                const float* xr0 = xps[s] + ((size_t)(brows[s] + r0) * SLEN + (t + 1)) * IDIM + o0;
                const float* xr1 = xr0 + (size_t)8 * SLEN * IDIM;
                pa = *(const float4*)xr0; pb = *(const float4*)(xr0 + 4);
                pc = *(const float4*)xr1; pd = *(const float4*)(xr1 + 4);
            }
            // ---- x-part GEMM (K=256): covers the h-load latency ----
            f32x4 acc0 = {bias0[0], bias0[1], bias0[2], bias0[3]};
            f32x4 acc1 = {bias1[0], bias1[1], bias1[2], bias1[3]};
            const _Float16* ab = &Ab[s][l16 * KP + quad * 8];
#pragma unroll
            for (int kk = 0; kk < 8; ++kk) {
                half8 bf = *(const half8*)(ab + kk * 32);
                acc0 = __builtin_amdgcn_mfma_f32_16x16x32_f16(wf0[kk], bf, acc0, 0, 0, 0);
                acc1 = __builtin_amdgcn_mfma_f32_16x16x32_f16(wf1[kk], bf, acc1, 0, 0, 0);
            }
            // ---- h staged: drain + barrier ----
            asm volatile("s_waitcnt vmcnt(0)" ::: "memory");
            __builtin_amdgcn_sched_barrier(0);
            __syncthreads();
            // ---- h-part GEMM (K=512) ----
#pragma unroll
            for (int kk = 8; kk < 24; ++kk) {
                half8 bf = *(const half8*)(ab + kk * 32);
                acc0 = __builtin_amdgcn_mfma_f32_16x16x32_f16(wf0[kk], bf, acc0, 0, 0, 0);
                acc1 = __builtin_amdgcn_mfma_f32_16x16x32_f16(wf1[kk], bf, acc1, 0, 0, 0);
            }
            // ---- cell update (regs 0..3 = i,f,g,o), fp32 ----
            float i0 = sigm(acc0[0]), f0 = sigm(acc0[1]), g0 = tanh_f(acc0[2]), o0g = sigm(acc0[3]);
            cr0[s] = f0 * cr0[s] + i0 * g0;
            float h0 = o0g * tanh_f(cr0[s]);
            float i1 = sigm(acc1[0]), f1 = sigm(acc1[1]), g1 = tanh_f(acc1[2]), o1g = sigm(acc1[3]);
            cr1[s] = f1 * cr1[s] + i1 * g1;
            float h1 = o1g * tanh_f(cr1[s]);

            if (t < NSTEP - 1) {
                // h store issued ASAP (drained at next body top)
                _Float16* hd = hb + (size_t)(t & 1) * (NROW * HDIM) + (size_t)grows[s] * HDIM;
                hu u0; u0.h = (_Float16)h0;
                hu u1; u1.h = (_Float16)h1;
                unsigned int hp = (unsigned int)u0.u | ((unsigned int)u1.u << 16);
                asm volatile("global_store_dword %0, %1, off sc0 sc1"
                             :: "v"((int*)(hd + cc0)), "v"(hp) : "memory");
                // x(t+1) stage (off-chain)
                *(half8*)&Ab[s][r0 * KP + o0]       = cvt8(pa, pb);
                *(half8*)&Ab[s][(r0 + 8) * KP + o0] = cvt8(pc, pd);
            } else {
                float2 ov; ov.x = h0; ov.y = h1;
                *(float2*)(out + (size_t)grows[s] * HDIM + cc0) = ov;
            }
            // ---- pre-issue next body's flag load (zero-init: premature copy
            //      reads 0 -> safe poll fallback) ----
            if (!(t == NSTEP - 1 && s == 1)) {
                asm volatile("v_mov_b32 %0, 0\n\t"
                             "global_load_dword %0, %1, off sc0 sc1"
                             : "=&v"(pf) : "v"(fpolls[1 - s]) : "memory");
            }
        }
    }
}

extern "C" void kernel_launch(void* const* d_in, const int* in_sizes, int n_in,
                              void* d_out, int out_size, void* d_ws, size_t ws_size,
                              hipStream_t stream) {
    const float* x0  = (const float*)d_in[0];   // [128,512,256] fp32
    const float* x1  = (const float*)d_in[1];
    const float* wih = (const float*)d_in[2];   // [2048,256]
    const float* whh = (const float*)d_in[3];   // [2048,512]
    const float* bih = (const float*)d_in[4];   // [2048]
    const float* bhh = (const float*)d_in[5];   // [2048]

    // ws: h ping-pong (2 x 256 KB f16) + per-(group,wave) flags (16 x 64 ints)
    _Float16* hb = (_Float16*)d_ws;
    int* flg = (int*)((char*)d_ws + (size_t)2 * NROW * HDIM * sizeof(_Float16));
    size_t zbytes = (size_t)2 * NROW * HDIM * sizeof(_Float16)
                  + (size_t)NGRP * 64 * sizeof(int);
    hipMemsetAsync(d_ws, 0, zbytes, stream);   // zero h_{-1} + flags (ws is 0xAA-poisoned)

    lstm_persistent<<<dim3(128), dim3(256), 0, stream>>>(
        x0, x1, wih, whh, bih, bhh, hb, flg, (float*)d_out);
}

// Round 5
// 2284.316 us; speedup vs baseline: 1.0837x; 1.0837x over previous
//
#include <hip/hip_runtime.h>
#include <stdint.h>

#define SLEN    512
#define IDIM    256
#define HDIM    512
#define NROW    256          // 2 sequences x 128 batch rows
#define KP      776          // Ab LDS row stride in halfs (768 + 8)
#define NSTEP   512
#define NGRP    16           // batch groups (16 rows each)
#define GWG     16           // WGs (column groups) per batch group
#define EXCH    256          // 8B (data,tag) chunks per batch row

typedef __attribute__((ext_vector_type(8))) _Float16 half8;
typedef __attribute__((ext_vector_type(4))) float   f32x4;
typedef __attribute__((ext_vector_type(4))) int     i32x4;
typedef __attribute__((ext_vector_type(2))) int     i32x2;

__device__ __forceinline__ float sigm(float x)   { return 1.0f / (1.0f + __expf(-x)); }
__device__ __forceinline__ float tanh_f(float x) { return 2.0f / (1.0f + __expf(-2.0f * x)) - 1.0f; }

__device__ __forceinline__ half8 cvt8(float4 a, float4 b) {
    half8 v;
    v[0] = (_Float16)a.x; v[1] = (_Float16)a.y; v[2] = (_Float16)a.z; v[3] = (_Float16)a.w;
    v[4] = (_Float16)b.x; v[5] = (_Float16)b.y; v[6] = (_Float16)b.z; v[7] = (_Float16)b.w;
    return v;
}
__device__ __forceinline__ half8 cvt8i(i32x4 a, i32x4 b) {
    float4 fa = *(float4*)&a, fb = *(float4*)&b;
    return cvt8(fa, fb);
}

union hu { _Float16 h; unsigned short u; };

// Round-5: tagged-data exchange (seqlock-free). The R1 flag protocol cost 3
// serial LLC RTs/step (poll, h-load, h-store-ack-before-flag). Here each lane
// stores its 2 f16 h-values + a 4B step tag as ONE aligned global_store_dwordx2
// (sc0 sc1): data+tag land atomically in the LLC line. Consumers load (data,tag)
// pairs directly and retry until all tags == t.
//   - store-ack RT off the chain (no flag to order against; store just flies)
//   - poll and h-load merge into one RT (first try usually succeeds: producers
//     post during the consumer's x-GEMM window)
//   - overwrite invariant (no flags needed): a WG stores h_t into buffer t&1
//     only after validating ALL tags==t, and each tag-t store was issued only
//     after its WG's barrier A2 at t-1, i.e. after that WG finished reading
//     buffer t&1 (h_{t-2}). Stale own-store reads simply retry (benign).
// Everything else (sc0 sc1 ops, GEMM layout, cell update) is the proven R1 base.
__global__ __launch_bounds__(256, 1)
void lstm_persistent(const float* __restrict__ x0, const float* __restrict__ x1,
                     const float* __restrict__ wih, const float* __restrict__ whh,
                     const float* __restrict__ bih, const float* __restrict__ bhh,
                     char* __restrict__ exb, float* __restrict__ out) {
    __shared__ __align__(16) _Float16 Ab[16 * KP];

    const int tid  = threadIdx.x;
    const int lane = tid & 63;
    const int w    = tid >> 6;       // wave 0..3
    const int quad = lane >> 4;
    const int l16  = lane & 15;
    const int igrp = blockIdx.x & 15;    // batch group (16 rows)
    const int jcg  = blockIdx.x >> 4;    // column group (32 H-cols)

    // ---- W A-frags: global fp32 -> f16 regs/AGPRs, once ----
    const int q0  = l16 & 3, ccl = l16 >> 2;
    const int colb = jcg * 32 + w * 8 + ccl * 2;
    const int gc0 = q0 * HDIM + colb;
    const int gc1 = gc0 + 1;
    half8 wf0[24], wf1[24];
#pragma unroll
    for (int kk = 0; kk < 24; ++kk) {
        int k0 = kk * 32 + quad * 8;
        const float* sA = (k0 < IDIM) ? wih + (size_t)gc0 * IDIM + k0
                                      : whh + (size_t)gc0 * HDIM + (k0 - IDIM);
        const float* sB = (k0 < IDIM) ? wih + (size_t)gc1 * IDIM + k0
                                      : whh + (size_t)gc1 * HDIM + (k0 - IDIM);
        wf0[kk] = cvt8(*(const float4*)sA, *(const float4*)(sA + 4));
        wf1[kk] = cvt8(*(const float4*)sB, *(const float4*)(sB + 4));
    }

    float bias0[4], bias1[4];
#pragma unroll
    for (int q = 0; q < 4; ++q) {
        int g0 = q * HDIM + jcg * 32 + w * 8 + quad * 2;
        bias0[q] = bih[g0] + bhh[g0];
        bias1[q] = bih[g0 + 1] + bhh[g0 + 1];
    }

    const float* xp  = (igrp < 8) ? x0 : x1;
    const int   brow = (igrp & 7) * 16;
    const int   r0   = tid >> 5;            // my x rows r0, r0+8
    const int   o0   = (tid & 31) * 8;      // my x col chunk
    const int   grow = igrp * 16 + l16;     // my batch row (global)
    const int   cc0  = jcg * 32 + w * 8 + quad * 2;   // my H-cols (cc0, cc0+1)

    // consumer staging assignment: row rr (0..15), chunk range [cb, cb+16)
    const int rr = tid >> 4;
    const int cb = (tid & 15) * 16;

    float c0 = 0.f, c1 = 0.f;
    int gaveup = 0;

    // ---- prologue: stage x(0) ----
    {
        const float* xr0 = xp + ((size_t)(brow + r0) * SLEN + 0) * IDIM + o0;
        const float* xr1 = xr0 + (size_t)8 * SLEN * IDIM;
        float4 pa = *(const float4*)xr0, pb = *(const float4*)(xr0 + 4);
        float4 pc = *(const float4*)xr1, pd = *(const float4*)(xr1 + 4);
        *(half8*)&Ab[r0 * KP + o0]       = cvt8(pa, pb);
        *(half8*)&Ab[(r0 + 8) * KP + o0] = cvt8(pc, pd);
    }
    __syncthreads();   // prologue full drain

#pragma unroll 1
    for (int t = 0; t < NSTEP; ++t) {
        // A1: x(t) ds_writes visible; all waves' step t-1 LDS reads done.
        // (h store from t-1 deliberately left in flight; drained by the
        //  consumer loop's vmcnt(0) below, concurrent with the tag loads.)
        asm volatile("s_waitcnt lgkmcnt(0)" ::: "memory");
        __builtin_amdgcn_sched_barrier(0);
        __builtin_amdgcn_s_barrier();

        // ---- x-part GEMM (K=256): covers producer skew ----
        f32x4 acc0 = {bias0[0], bias0[1], bias0[2], bias0[3]};
        f32x4 acc1 = {bias1[0], bias1[1], bias1[2], bias1[3]};
        const _Float16* ab = &Ab[l16 * KP + quad * 8];
#pragma unroll
        for (int kk = 0; kk < 8; ++kk) {
            half8 bf = *(const half8*)(ab + kk * 32);
            acc0 = __builtin_amdgcn_mfma_f32_16x16x32_f16(wf0[kk], bf, acc0, 0, 0, 0);
            acc1 = __builtin_amdgcn_mfma_f32_16x16x32_f16(wf1[kk], bf, acc1, 0, 0, 0);
        }

        // ---- x(t+1) prefetch issue (asm: pinned before the consumer loop;
        //      its drain folds into the loop's first vmcnt(0)) ----
        i32x4 xv0, xv1, xv2, xv3;
        if (t < NSTEP - 1) {
            const float* xr0 = xp + ((size_t)(brow + r0) * SLEN + (t + 1)) * IDIM + o0;
            const float* xr1 = xr0 + (size_t)8 * SLEN * IDIM;
            asm volatile(
                "global_load_dwordx4 %0, %4, off\n\t"
                "global_load_dwordx4 %1, %4, off offset:16\n\t"
                "global_load_dwordx4 %2, %5, off\n\t"
                "global_load_dwordx4 %3, %5, off offset:16"
                : "=&v"(xv0), "=&v"(xv1), "=&v"(xv2), "=&v"(xv3)
                : "v"(xr0), "v"(xr1)
                : "memory");
        }

        // ---- consumer: tagged h_{t-1} read (retry until all tags == t) ----
        i32x4 L0, L1, L2, L3, L4, L5, L6, L7;
        {
            const char* base = exb
                + ((size_t)(((t + 1) & 1) * NROW + igrp * 16 + rr) * EXCH + cb) * 8;
            int it = 0;
            while (true) {
                asm volatile(
                    "global_load_dwordx4 %0, %8, off sc0 sc1\n\t"
                    "global_load_dwordx4 %1, %8, off offset:16 sc0 sc1\n\t"
                    "global_load_dwordx4 %2, %8, off offset:32 sc0 sc1\n\t"
                    "global_load_dwordx4 %3, %8, off offset:48 sc0 sc1\n\t"
                    "global_load_dwordx4 %4, %8, off offset:64 sc0 sc1\n\t"
                    "global_load_dwordx4 %5, %8, off offset:80 sc0 sc1\n\t"
                    "global_load_dwordx4 %6, %8, off offset:96 sc0 sc1\n\t"
                    "global_load_dwordx4 %7, %8, off offset:112 sc0 sc1\n\t"
                    "s_waitcnt vmcnt(0)"
                    : "=&v"(L0), "=&v"(L1), "=&v"(L2), "=&v"(L3),
                      "=&v"(L4), "=&v"(L5), "=&v"(L6), "=&v"(L7)
                    : "v"(base)
                    : "memory");
                int ok = (L0[1] == t) & (L0[3] == t) & (L1[1] == t) & (L1[3] == t)
                       & (L2[1] == t) & (L2[3] == t) & (L3[1] == t) & (L3[3] == t)
                       & (L4[1] == t) & (L4[3] == t) & (L5[1] == t) & (L5[3] == t)
                       & (L6[1] == t) & (L6[3] == t) & (L7[1] == t) & (L7[3] == t);
                if (__all(ok)) break;
                __builtin_amdgcn_s_sleep(1);
                if (++it > (1 << 16)) { gaveup = 1; break; }
            }
            __builtin_amdgcn_fence(__ATOMIC_ACQUIRE, "workgroup");
            // stage: chunk pair j -> halfs [2*(cb+2j) .. +3] of row rr
            i32x2 s0; s0[0] = L0[0]; s0[1] = L0[2];
            i32x2 s1; s1[0] = L1[0]; s1[1] = L1[2];
            i32x2 s2; s2[0] = L2[0]; s2[1] = L2[2];
            i32x2 s3; s3[0] = L3[0]; s3[1] = L3[2];
            i32x2 s4; s4[0] = L4[0]; s4[1] = L4[2];
            i32x2 s5; s5[0] = L5[0]; s5[1] = L5[2];
            i32x2 s6; s6[0] = L6[0]; s6[1] = L6[2];
            i32x2 s7; s7[0] = L7[0]; s7[1] = L7[2];
            _Float16* hrow = &Ab[rr * KP + IDIM + 2 * cb];
            *(i32x2*)(hrow +  0) = s0;
            *(i32x2*)(hrow +  4) = s1;
            *(i32x2*)(hrow +  8) = s2;
            *(i32x2*)(hrow + 12) = s3;
            *(i32x2*)(hrow + 16) = s4;
            *(i32x2*)(hrow + 20) = s5;
            *(i32x2*)(hrow + 24) = s6;
            *(i32x2*)(hrow + 28) = s7;
        }
        asm volatile("s_waitcnt lgkmcnt(0)" ::: "memory");
        __builtin_amdgcn_sched_barrier(0);
        __builtin_amdgcn_s_barrier();   // A2: h staged for all waves

        // ---- h-part GEMM (K=512) ----
#pragma unroll
        for (int kk = 8; kk < 24; ++kk) {
            half8 bf = *(const half8*)(ab + kk * 32);
            acc0 = __builtin_amdgcn_mfma_f32_16x16x32_f16(wf0[kk], bf, acc0, 0, 0, 0);
            acc1 = __builtin_amdgcn_mfma_f32_16x16x32_f16(wf1[kk], bf, acc1, 0, 0, 0);
        }

        // ---- cell update (regs 0..3 = i,f,g,o), fp32 ----
        float i0 = sigm(acc0[0]), f0 = sigm(acc0[1]), g0 = tanh_f(acc0[2]), o0g = sigm(acc0[3]);
        c0 = f0 * c0 + i0 * g0;
        float h0 = o0g * tanh_f(c0);
        float i1 = sigm(acc1[0]), f1 = sigm(acc1[1]), g1 = tanh_f(acc1[2]), o1g = sigm(acc1[3]);
        c1 = f1 * c1 + i1 * g1;
        float h1 = o1g * tanh_f(c1);

        if (t < NSTEP - 1) {
            // tagged store: {2 f16 h, tag=t+1} in ONE dwordx2 -> no drain, no flag
            hu u0; u0.h = (_Float16)h0;
            hu u1; u1.h = (_Float16)h1;
            i32x2 sv;
            sv[0] = (int)((unsigned int)u0.u | ((unsigned int)u1.u << 16));
            sv[1] = t + 1;
            char* dst = exb + ((size_t)((t & 1) * NROW + grow) * EXCH + (cc0 >> 1)) * 8;
            asm volatile("global_store_dwordx2 %0, %1, off sc0 sc1"
                         :: "v"(dst), "v"(sv) : "memory");
            // x(t+1) stage (values guaranteed resident: consumer loop drained vmcnt)
            *(half8*)&Ab[r0 * KP + o0]       = cvt8i(xv0, xv1);
            *(half8*)&Ab[(r0 + 8) * KP + o0] = cvt8i(xv2, xv3);
        } else {
            float2 ov; ov.x = h0; ov.y = h1;
            *(float2*)(out + (size_t)grow * HDIM + cc0) = ov;
        }
        if (gaveup) break;   // failsafe: never hang
    }
}

extern "C" void kernel_launch(void* const* d_in, const int* in_sizes, int n_in,
                              void* d_out, int out_size, void* d_ws, size_t ws_size,
                              hipStream_t stream) {
    const float* x0  = (const float*)d_in[0];   // [128,512,256] fp32
    const float* x1  = (const float*)d_in[1];
    const float* wih = (const float*)d_in[2];   // [2048,256]
    const float* whh = (const float*)d_in[3];   // [2048,512]
    const float* bih = (const float*)d_in[4];   // [2048]
    const float* bhh = (const float*)d_in[5];   // [2048]

    // ws: tagged exchange buffer, ping-pong: 2 x 256 rows x 256 chunks x 8B = 1 MB
    char* exb = (char*)d_ws;
    size_t zbytes = (size_t)2 * NROW * EXCH * 8;
    hipMemsetAsync(d_ws, 0, zbytes, stream);   // tags=0 == expected at t=0; h_{-1}=0

    lstm_persistent<<<dim3(256), dim3(256), 0, stream>>>(
        x0, x1, wih, whh, bih, bhh, exb, (float*)d_out);
}

// Round 6
// 1562.594 us; speedup vs baseline: 1.5842x; 1.4619x over previous
//
#include <hip/hip_runtime.h>
#include <stdint.h>

#define SLEN    512
#define IDIM    256
#define HDIM    512
#define NROW    256          // 2 sequences x 128 batch rows
#define KP      776          // Ab LDS row stride in halfs (768 + 8)
#define NSTEP   512
#define NGRP    16           // batch groups (16 rows each)
#define GWG     16           // WGs (column groups) per batch group

typedef __attribute__((ext_vector_type(8))) _Float16 half8;
typedef __attribute__((ext_vector_type(4))) float   f32x4;
typedef __attribute__((ext_vector_type(4))) int     i32x4;

#define AS1 __attribute__((address_space(1)))
#define AS3 __attribute__((address_space(3)))

__device__ __forceinline__ float sigm(float x)   { return 1.0f / (1.0f + __expf(-x)); }
__device__ __forceinline__ float tanh_f(float x) { return 2.0f / (1.0f + __expf(-2.0f * x)) - 1.0f; }

__device__ __forceinline__ half8 cvt8(float4 a, float4 b) {
    half8 v;
    v[0] = (_Float16)a.x; v[1] = (_Float16)a.y; v[2] = (_Float16)a.z; v[3] = (_Float16)a.w;
    v[4] = (_Float16)b.x; v[5] = (_Float16)b.y; v[6] = (_Float16)b.z; v[7] = (_Float16)b.w;
    return v;
}
__device__ __forceinline__ half8 cvt8i(i32x4 a, i32x4 b) {
    float4 fa = *(float4*)&a, fb = *(float4*)&b;
    return cvt8(fa, fb);
}

union hu { _Float16 h; unsigned short u; };

// Round-6: R1's proven flag protocol (compact signal, bulk data moves once)
// with the serial chain trimmed. R5's post-mortem: fat retry units (32KB/WG)
// storm the LLC -> keep polls at 256B/WG (R1 flags). Changes vs R1 (each
// mechanism already validated in a passing run):
//  1. x(t+1) prefetch issued AFTER the h-load drain -> the poll loop's
//     vmcnt(0) no longer waits ~900cy of HBM latency before reading flags;
//     x-loads fly across A2 (register loads) and drain in the pre-flag
//     vmcnt(0), hidden under h-GEMM+cell.
//  2. flag posted before x-stage (store -> drain -> flag -> x-stage): peers
//     are blocked on the flag, not on my x staging.
//  3. raw s_barrier + lgkmcnt(0) (validated by R5 pass) and global_load_lds
//     aux=17 h-staging (validated by R2 pass; no LDS scatter writes).
__global__ __launch_bounds__(256, 1)
void lstm_persistent(const float* __restrict__ x0, const float* __restrict__ x1,
                     const float* __restrict__ wih, const float* __restrict__ whh,
                     const float* __restrict__ bih, const float* __restrict__ bhh,
                     _Float16* __restrict__ hb, int* __restrict__ flg,
                     float* __restrict__ out) {
    __shared__ __align__(16) _Float16 Ab[16 * KP];

    const int tid  = threadIdx.x;
    const int lane = tid & 63;
    const int w    = tid >> 6;       // wave 0..3
    const int quad = lane >> 4;
    const int l16  = lane & 15;
    const int igrp = blockIdx.x & 15;    // batch group (16 rows)
    const int jcg  = blockIdx.x >> 4;    // column group (32 H-cols)

    // ---- W A-frags: global fp32 -> f16 regs/AGPRs, once ----
    const int q0  = l16 & 3, ccl = l16 >> 2;
    const int colb = jcg * 32 + w * 8 + ccl * 2;
    const int gc0 = q0 * HDIM + colb;
    const int gc1 = gc0 + 1;
    half8 wf0[24], wf1[24];
#pragma unroll
    for (int kk = 0; kk < 24; ++kk) {
        int k0 = kk * 32 + quad * 8;
        const float* sA = (k0 < IDIM) ? wih + (size_t)gc0 * IDIM + k0
                                      : whh + (size_t)gc0 * HDIM + (k0 - IDIM);
        const float* sB = (k0 < IDIM) ? wih + (size_t)gc1 * IDIM + k0
                                      : whh + (size_t)gc1 * HDIM + (k0 - IDIM);
        wf0[kk] = cvt8(*(const float4*)sA, *(const float4*)(sA + 4));
        wf1[kk] = cvt8(*(const float4*)sB, *(const float4*)(sB + 4));
    }

    float bias0[4], bias1[4];
#pragma unroll
    for (int q = 0; q < 4; ++q) {
        int g0 = q * HDIM + jcg * 32 + w * 8 + quad * 2;
        bias0[q] = bih[g0] + bhh[g0];
        bias1[q] = bih[g0 + 1] + bhh[g0 + 1];
    }

    const float* xp  = (igrp < 8) ? x0 : x1;
    const int   brow = (igrp & 7) * 16;
    const int   r0   = tid >> 5;            // my x rows r0, r0+8
    const int   o0   = (tid & 31) * 8;      // my x col chunk
    const int   grow = igrp * 16 + l16;     // my batch row (global)
    const int   cc0  = jcg * 32 + w * 8 + quad * 2;   // my H-cols (cc0, cc0+1)

    const int* fpoll = flg + igrp * 64 + lane;          // 64 wave-flags of my group
    int*       fmine = flg + igrp * 64 + jcg * 4 + w;   // my wave's flag

    float c0 = 0.f, c1 = 0.f;
    int gaveup = 0;

    // ---- prologue: stage x(0) ----
    {
        const float* xr0 = xp + ((size_t)(brow + r0) * SLEN + 0) * IDIM + o0;
        const float* xr1 = xr0 + (size_t)8 * SLEN * IDIM;
        float4 pa = *(const float4*)xr0, pb = *(const float4*)(xr0 + 4);
        float4 pc = *(const float4*)xr1, pd = *(const float4*)(xr1 + 4);
        *(half8*)&Ab[r0 * KP + o0]       = cvt8(pa, pb);
        *(half8*)&Ab[(r0 + 8) * KP + o0] = cvt8(pc, pd);
    }
    __syncthreads();   // prologue full drain

#pragma unroll 1
    for (int t = 0; t < NSTEP; ++t) {
        if (t > 0) {
            // A1: x(t) ds_writes visible; all waves' step t-1 LDS reads done.
            asm volatile("s_waitcnt lgkmcnt(0)" ::: "memory");
            __builtin_amdgcn_sched_barrier(0);
            __builtin_amdgcn_s_barrier();
        }

        // ---- x-part GEMM (K=256): covers producer skew ----
        f32x4 acc0 = {bias0[0], bias0[1], bias0[2], bias0[3]};
        f32x4 acc1 = {bias1[0], bias1[1], bias1[2], bias1[3]};
        const _Float16* ab = &Ab[l16 * KP + quad * 8];
#pragma unroll
        for (int kk = 0; kk < 8; ++kk) {
            half8 bf = *(const half8*)(ab + kk * 32);
            acc0 = __builtin_amdgcn_mfma_f32_16x16x32_f16(wf0[kk], bf, acc0, 0, 0, 0);
            acc1 = __builtin_amdgcn_mfma_f32_16x16x32_f16(wf1[kk], bf, acc1, 0, 0, 0);
        }

        // ---- poll: all 64 producer waves signalled step t-1 (256B/WG/retry;
        //      vmem queue is empty here -> retry RT = pure flag load) ----
        if (t > 0 && !gaveup) {
            int it = 0;
            while (true) {
                int f;
                asm volatile("global_load_dword %0, %1, off sc0 sc1\n\t"
                             "s_waitcnt vmcnt(0)"
                             : "=&v"(f) : "v"(fpoll) : "memory");
                if (__all(f >= t)) break;
                __builtin_amdgcn_s_sleep(1);
                if (++it > (1 << 20)) { gaveup = 1; break; }
            }
            __builtin_amdgcn_fence(__ATOMIC_ACQUIRE, "workgroup");
        }

        // ---- h_{t-1} staging: 4x global_load_lds (aux=17), full drain ----
        {
            const _Float16* hsrc = hb + (size_t)((t + 1) & 1) * (NROW * HDIM)
                                      + (size_t)(igrp * 16) * HDIM;
#pragma unroll
            for (int p = 0; p < 4; ++p) {
                const int r = p * 4 + w;
                const _Float16* g = hsrc + (size_t)r * HDIM + lane * 8;
                __builtin_amdgcn_global_load_lds(
                    (const AS1 void*)g, (AS3 void*)&Ab[r * KP + IDIM],
                    16, 0, 17);
            }
            asm volatile("s_waitcnt vmcnt(0)" ::: "memory");
            __builtin_amdgcn_sched_barrier(0);
        }

        // ---- x(t+1) prefetch: issued AFTER h drain -> flies across A2;
        //      drained by the pre-flag vmcnt(0), hidden under hGEMM+cell ----
        i32x4 xv0, xv1, xv2, xv3;
        if (t < NSTEP - 1) {
            const float* xr0 = xp + ((size_t)(brow + r0) * SLEN + (t + 1)) * IDIM + o0;
            const float* xr1 = xr0 + (size_t)8 * SLEN * IDIM;
            asm volatile(
                "global_load_dwordx4 %0, %4, off\n\t"
                "global_load_dwordx4 %1, %4, off offset:16\n\t"
                "global_load_dwordx4 %2, %5, off\n\t"
                "global_load_dwordx4 %3, %5, off offset:16"
                : "=&v"(xv0), "=&v"(xv1), "=&v"(xv2), "=&v"(xv3)
                : "v"(xr0), "v"(xr1)
                : "memory");
        }
        __builtin_amdgcn_sched_barrier(0);
        __builtin_amdgcn_s_barrier();   // A2: h staged for all waves

        // ---- h-part GEMM (K=512) ----
#pragma unroll
        for (int kk = 8; kk < 24; ++kk) {
            half8 bf = *(const half8*)(ab + kk * 32);
            acc0 = __builtin_amdgcn_mfma_f32_16x16x32_f16(wf0[kk], bf, acc0, 0, 0, 0);
            acc1 = __builtin_amdgcn_mfma_f32_16x16x32_f16(wf1[kk], bf, acc1, 0, 0, 0);
        }

        // ---- cell update (regs 0..3 = i,f,g,o), fp32 ----
        float i0 = sigm(acc0[0]), f0 = sigm(acc0[1]), g0 = tanh_f(acc0[2]), o0g = sigm(acc0[3]);
        c0 = f0 * c0 + i0 * g0;
        float h0 = o0g * tanh_f(c0);
        float i1 = sigm(acc1[0]), f1 = sigm(acc1[1]), g1 = tanh_f(acc1[2]), o1g = sigm(acc1[3]);
        c1 = f1 * c1 + i1 * g1;
        float h1 = o1g * tanh_f(c1);

        if (t < NSTEP - 1) {
            // h store -> drain (store-ack overlaps x-prefetch residual) ->
            // flag (ASAP: peers are blocked on it) -> x-stage (local)
            _Float16* hd = hb + (size_t)(t & 1) * (NROW * HDIM) + (size_t)grow * HDIM;
            hu u0; u0.h = (_Float16)h0;
            hu u1; u1.h = (_Float16)h1;
            unsigned int hp = (unsigned int)u0.u | ((unsigned int)u1.u << 16);
            asm volatile("global_store_dword %0, %1, off sc0 sc1"
                         :: "v"((int*)(hd + cc0)), "v"(hp) : "memory");
            __builtin_amdgcn_sched_barrier(0);
            asm volatile("s_waitcnt vmcnt(0)" ::: "memory");
            __builtin_amdgcn_sched_barrier(0);
            if (lane == 0) {
                int fv = t + 1;
                asm volatile("global_store_dword %0, %1, off sc0 sc1"
                             :: "v"(fmine), "v"(fv) : "memory");
            }
            // x(t+1) stage (regs already resident; ds only, covered by next A1)
            *(half8*)&Ab[r0 * KP + o0]       = cvt8i(xv0, xv1);
            *(half8*)&Ab[(r0 + 8) * KP + o0] = cvt8i(xv2, xv3);
        } else {
            float2 ov; ov.x = h0; ov.y = h1;
            *(float2*)(out + (size_t)grow * HDIM + cc0) = ov;
        }
    }
}

extern "C" void kernel_launch(void* const* d_in, const int* in_sizes, int n_in,
                              void* d_out, int out_size, void* d_ws, size_t ws_size,
                              hipStream_t stream) {
    const float* x0  = (const float*)d_in[0];   // [128,512,256] fp32
    const float* x1  = (const float*)d_in[1];
    const float* wih = (const float*)d_in[2];   // [2048,256]
    const float* whh = (const float*)d_in[3];   // [2048,512]
    const float* bih = (const float*)d_in[4];   // [2048]
    const float* bhh = (const float*)d_in[5];   // [2048]

    // ws: h ping-pong (2 x 256 KB f16) + per-(group,wave) flags (16 x 64 ints)
    _Float16* hb = (_Float16*)d_ws;
    int* flg = (int*)((char*)d_ws + (size_t)2 * NROW * HDIM * sizeof(_Float16));
    size_t zbytes = (size_t)2 * NROW * HDIM * sizeof(_Float16)
                  + (size_t)NGRP * 64 * sizeof(int);
    hipMemsetAsync(d_ws, 0, zbytes, stream);   // zero h_{-1} + flags

    lstm_persistent<<<dim3(256), dim3(256), 0, stream>>>(
        x0, x1, wih, whh, bih, bhh, hb, flg, (float*)d_out);
}